// Round 1
// baseline (2464.728 us; speedup 1.0000x reference)
//
#include <hip/hip_runtime.h>
#include <hip/hip_bf16.h>

// Problem constants (match reference setup_inputs)
static constexpr int N = 100000;
static constexpr int E = 600000;
static constexpr int D = 128;
static constexpr int B = 10000;
static constexpr int C = 32;

// ---------------- edge kernels ----------------

__global__ void count_k(const int* __restrict__ dst, float* __restrict__ cnt, int nE) {
    int i = blockIdx.x * blockDim.x + threadIdx.x;
    if (i < nE) atomicAdd(&cnt[dst[i]], 1.0f);
}

// one edge handled by 32 threads, each does a float4 chunk (4 scalar atomics)
__global__ void scatter_k(const float* __restrict__ x, const int* __restrict__ src,
                          const int* __restrict__ dst, float* __restrict__ agg, int nE) {
    long tid = (long)blockIdx.x * blockDim.x + threadIdx.x;
    int e = (int)(tid >> 5);
    int p = (int)(tid & 31);
    if (e >= nE) return;
    int s = src[e];
    int d = dst[e];
    const float4 v = *reinterpret_cast<const float4*>(x + (long)s * D + p * 4);
    float* a = agg + (long)d * D + p * 4;
    atomicAdd(a + 0, v.x);
    atomicAdd(a + 1, v.y);
    atomicAdd(a + 2, v.z);
    atomicAdd(a + 3, v.w);
}

// ---------------- SAGE layer GEMM ----------------
// xout[row] = relu( (agg[grow]/max(cnt[grow],1)) @ Wl + bl + xin[grow] @ Wr )
// GATHER=false: grow = row (full N rows, compact out)
// GATHER=true : grow = rows[row]  (B gathered rows, compact out)
template <bool GATHER>
__global__ __launch_bounds__(256) void sage_gemm_k(
    const float* __restrict__ agg, const float* __restrict__ cnt,
    const float* __restrict__ xin, const int* __restrict__ rows,
    const float* __restrict__ Wl, const float* __restrict__ bl,
    const float* __restrict__ Wr, float* __restrict__ xout, int nrows) {
    __shared__ float Am[32][128];
    __shared__ float Ax[32][128];
    const int rb = blockIdx.x * 32;
    const int t  = threadIdx.x;

    // stage 32-row tile of mean and x into LDS (float4 loads, coalesced)
    #pragma unroll
    for (int it = 0; it < 4; ++it) {
        int j  = t + it * 256;   // float4 index within tile, 0..1023
        int r  = j >> 5;         // 0..31
        int k4 = j & 31;         // 0..31
        int row = rb + r;
        float4 a4 = make_float4(0.f, 0.f, 0.f, 0.f);
        float4 x4 = make_float4(0.f, 0.f, 0.f, 0.f);
        if (row < nrows) {
            int grow = GATHER ? rows[row] : row;
            float inv = 1.0f / fmaxf(cnt[grow], 1.0f);
            a4 = *reinterpret_cast<const float4*>(agg + (long)grow * D + k4 * 4);
            a4.x *= inv; a4.y *= inv; a4.z *= inv; a4.w *= inv;
            x4 = *reinterpret_cast<const float4*>(xin + (long)grow * D + k4 * 4);
        }
        *reinterpret_cast<float4*>(&Am[r][k4 * 4]) = a4;
        *reinterpret_cast<float4*>(&Ax[r][k4 * 4]) = x4;
    }
    __syncthreads();

    const int col  = t & 127;
    const int half = t >> 7;  // 0 or 1: rows half*16 .. half*16+15
    float acc[16];
    const float bias = bl[col];
    #pragma unroll
    for (int i = 0; i < 16; ++i) acc[i] = bias;

    for (int k = 0; k < 128; ++k) {
        float wl = Wl[k * 128 + col];
        float wr = Wr[k * 128 + col];
        #pragma unroll
        for (int i = 0; i < 16; ++i) {
            int r = half * 16 + i;
            acc[i] = fmaf(Am[r][k], wl, fmaf(Ax[r][k], wr, acc[i]));
        }
    }

    #pragma unroll
    for (int i = 0; i < 16; ++i) {
        int row = rb + half * 16 + i;
        if (row < nrows) xout[(long)row * D + col] = fmaxf(acc[i], 0.0f);
    }
}

// ---------------- classifier: out = relu(x2g@Wc1+bc1) @ Wc2 + bc2 ----------------
__global__ __launch_bounds__(256) void classifier_k(
    const float* __restrict__ x2g,
    const float* __restrict__ Wc1, const float* __restrict__ bc1,
    const float* __restrict__ Wc2, const float* __restrict__ bc2,
    float* __restrict__ out, int nrows) {
    __shared__ float Xs[32][128];
    __shared__ float Hs[32][128];
    const int rb = blockIdx.x * 32;
    const int t  = threadIdx.x;

    #pragma unroll
    for (int it = 0; it < 4; ++it) {
        int j  = t + it * 256;
        int r  = j >> 5;
        int k4 = j & 31;
        int row = rb + r;
        float4 v = make_float4(0.f, 0.f, 0.f, 0.f);
        if (row < nrows) v = *reinterpret_cast<const float4*>(x2g + (long)row * D + k4 * 4);
        *reinterpret_cast<float4*>(&Xs[r][k4 * 4]) = v;
    }
    __syncthreads();

    {
        const int col  = t & 127;
        const int half = t >> 7;
        float acc[16];
        const float bias = bc1[col];
        #pragma unroll
        for (int i = 0; i < 16; ++i) acc[i] = bias;
        for (int k = 0; k < 128; ++k) {
            float w = Wc1[k * 128 + col];
            #pragma unroll
            for (int i = 0; i < 16; ++i)
                acc[i] = fmaf(Xs[half * 16 + i][k], w, acc[i]);
        }
        #pragma unroll
        for (int i = 0; i < 16; ++i)
            Hs[half * 16 + i][col] = fmaxf(acc[i], 0.0f);
    }
    __syncthreads();

    {
        const int c  = t & 31;   // class
        const int rg = t >> 5;   // 0..7; rows rg, rg+8, rg+16, rg+24
        float o[4];
        const float b2 = bc2[c];
        #pragma unroll
        for (int i = 0; i < 4; ++i) o[i] = b2;
        for (int k = 0; k < 128; ++k) {
            float w = Wc2[k * 32 + c];
            #pragma unroll
            for (int i = 0; i < 4; ++i)
                o[i] = fmaf(Hs[rg + 8 * i][k], w, o[i]);
        }
        #pragma unroll
        for (int i = 0; i < 4; ++i) {
            int row = rb + rg + 8 * i;
            if (row < nrows) out[(long)row * C + c] = o[i];
        }
    }
}

// ---------------- launch ----------------

extern "C" void kernel_launch(void* const* d_in, const int* in_sizes, int n_in,
                              void* d_out, int out_size, void* d_ws, size_t ws_size,
                              hipStream_t stream) {
    const float* node_state = (const float*)d_in[0];
    const int*   edge_index = (const int*)d_in[1];
    const int*   label_pos  = (const int*)d_in[2];
    const float* W1l = (const float*)d_in[3];
    const float* b1l = (const float*)d_in[4];
    const float* W1r = (const float*)d_in[5];
    const float* W2l = (const float*)d_in[6];
    const float* b2l = (const float*)d_in[7];
    const float* W2r = (const float*)d_in[8];
    const float* Wc1 = (const float*)d_in[9];
    const float* bc1 = (const float*)d_in[10];
    const float* Wc2 = (const float*)d_in[11];
    const float* bc2 = (const float*)d_in[12];
    float* out = (float*)d_out;

    const int* src = edge_index;       // edge_index[0]
    const int* dst = edge_index + E;   // edge_index[1]

    // workspace layout (floats)
    float* ws   = (float*)d_ws;
    float* agg  = ws;                          // N*D
    float* cnt  = agg + (size_t)N * D;         // N
    float* x1   = cnt + N;                     // N*D
    float* x2g  = x1 + (size_t)N * D;          // B*D
    // total: N*D + N + N*D + B*D = 25.7M + 1.28M floats ≈ 108 MB

    const int TB = 256;
    const int scatterBlocks = (int)(((long)E * 32 + TB - 1) / TB);

    // ---- layer 1 ----
    hipMemsetAsync(agg, 0, (size_t)N * D * sizeof(float), stream);
    hipMemsetAsync(cnt, 0, (size_t)N * sizeof(float), stream);
    count_k<<<(E + TB - 1) / TB, TB, 0, stream>>>(dst, cnt, E);
    scatter_k<<<scatterBlocks, TB, 0, stream>>>(node_state, src, dst, agg, E);
    sage_gemm_k<false><<<(N + 31) / 32, TB, 0, stream>>>(
        agg, cnt, node_state, nullptr, W1l, b1l, W1r, x1, N);

    // ---- layer 2 (output only at label_pos rows) ----
    hipMemsetAsync(agg, 0, (size_t)N * D * sizeof(float), stream);
    scatter_k<<<scatterBlocks, TB, 0, stream>>>(x1, src, dst, agg, E);
    sage_gemm_k<true><<<(B + 31) / 32, TB, 0, stream>>>(
        agg, cnt, x1, label_pos, W2l, b2l, W2r, x2g, B);

    // ---- classifier ----
    classifier_k<<<(B + 31) / 32, TB, 0, stream>>>(x2g, Wc1, bc1, Wc2, bc2, out, B);
}

// Round 2
// 734.848 us; speedup vs baseline: 3.3541x; 3.3541x over previous
//
#include <hip/hip_runtime.h>
#include <hip/hip_bf16.h>

// Problem constants (match reference setup_inputs)
static constexpr int N = 100000;
static constexpr int E = 600000;
static constexpr int D = 128;
static constexpr int B = 10000;
static constexpr int C = 32;

// ---------------- CSR build ----------------

__global__ void deg_k(const int* __restrict__ dst, int* __restrict__ deg, int nE) {
    int i = blockIdx.x * blockDim.x + threadIdx.x;
    if (i < nE) atomicAdd(&deg[dst[i]], 1);
}

// single-block exclusive scan over N elements -> roff[N+1]; also copies to cur
__global__ __launch_bounds__(1024) void scan_k(const int* __restrict__ deg,
                                               int* __restrict__ roff,
                                               int* __restrict__ cur, int n) {
    __shared__ int sums[1024];
    const int t = threadIdx.x;
    const int chunk = (n + 1023) / 1024;
    const int lo = t * chunk;
    const int hi = min(lo + chunk, n);
    int s = 0;
    for (int i = lo; i < hi; ++i) s += deg[i];
    sums[t] = s;
    __syncthreads();
    for (int off = 1; off < 1024; off <<= 1) {
        int v = (t >= off) ? sums[t - off] : 0;
        __syncthreads();
        sums[t] += v;
        __syncthreads();
    }
    int run = sums[t] - s;   // exclusive prefix of this thread's chunk
    for (int i = lo; i < hi; ++i) {
        roff[i] = run;
        cur[i]  = run;
        run += deg[i];
    }
    if (t == 1023) roff[n] = run;   // last thread's run == total (empty chunks ok)
}

__global__ void fill_k(const int* __restrict__ src, const int* __restrict__ dst,
                       int* __restrict__ cur, int* __restrict__ csr_src, int nE) {
    int e = blockIdx.x * blockDim.x + threadIdx.x;
    if (e < nE) {
        int p = atomicAdd(&cur[dst[e]], 1);
        csr_src[p] = src[e];
    }
}

// ---------------- gather-mean aggregation ----------------
// one wave (64 lanes) per output row; lane handles 2 floats (float2) of D=128.
// GATHER=false: node = row (all N). GATHER=true: node = rows[row] (B labels).
template <bool GATHER>
__global__ __launch_bounds__(256) void gather_mean_k(
    const float* __restrict__ x, const int* __restrict__ roff,
    const int* __restrict__ csr_src, const int* __restrict__ rows,
    float* __restrict__ out, int nrows) {
    const int w = blockIdx.x * (blockDim.x >> 6) + (threadIdx.x >> 6);
    if (w >= nrows) return;
    const int lane = threadIdx.x & 63;
    const int n  = GATHER ? rows[w] : w;
    const int jb = roff[n];
    const int je = roff[n + 1];
    const float* xb = x + lane * 2;

    float ax = 0.f, ay = 0.f;
    int j = jb;
    for (; j + 4 <= je; j += 4) {
        int s0 = csr_src[j + 0];
        int s1 = csr_src[j + 1];
        int s2 = csr_src[j + 2];
        int s3 = csr_src[j + 3];
        float2 v0 = *reinterpret_cast<const float2*>(xb + (size_t)s0 * D);
        float2 v1 = *reinterpret_cast<const float2*>(xb + (size_t)s1 * D);
        float2 v2 = *reinterpret_cast<const float2*>(xb + (size_t)s2 * D);
        float2 v3 = *reinterpret_cast<const float2*>(xb + (size_t)s3 * D);
        ax += v0.x + v1.x + v2.x + v3.x;
        ay += v0.y + v1.y + v2.y + v3.y;
    }
    for (; j < je; ++j) {
        int s = csr_src[j];
        float2 v = *reinterpret_cast<const float2*>(xb + (size_t)s * D);
        ax += v.x;
        ay += v.y;
    }
    const float inv = 1.0f / fmaxf((float)(je - jb), 1.0f);
    *reinterpret_cast<float2*>(out + (size_t)w * D + lane * 2) =
        make_float2(ax * inv, ay * inv);
}

// ---------------- SAGE layer GEMM ----------------
// xout[row] = relu( mean[row] @ Wl + bl + xin[grow] @ Wr )
// mean is compact [nrows][D]; xin indexed by grow (= rows[row] if GATHER else row)
template <bool GATHER>
__global__ __launch_bounds__(256) void sage_gemm_k(
    const float* __restrict__ mean, const float* __restrict__ xin,
    const int* __restrict__ rows,
    const float* __restrict__ Wl, const float* __restrict__ bl,
    const float* __restrict__ Wr, float* __restrict__ xout, int nrows) {
    __shared__ float Am[32][128];
    __shared__ float Ax[32][128];
    const int rb = blockIdx.x * 32;
    const int t  = threadIdx.x;

    #pragma unroll
    for (int it = 0; it < 4; ++it) {
        int j  = t + it * 256;   // float4 index within tile, 0..1023
        int r  = j >> 5;         // 0..31
        int k4 = j & 31;         // 0..31
        int row = rb + r;
        float4 a4 = make_float4(0.f, 0.f, 0.f, 0.f);
        float4 x4 = make_float4(0.f, 0.f, 0.f, 0.f);
        if (row < nrows) {
            int grow = GATHER ? rows[row] : row;
            a4 = *reinterpret_cast<const float4*>(mean + (size_t)row * D + k4 * 4);
            x4 = *reinterpret_cast<const float4*>(xin + (size_t)grow * D + k4 * 4);
        }
        *reinterpret_cast<float4*>(&Am[r][k4 * 4]) = a4;
        *reinterpret_cast<float4*>(&Ax[r][k4 * 4]) = x4;
    }
    __syncthreads();

    const int col  = t & 127;
    const int half = t >> 7;  // 0 or 1: rows half*16 .. half*16+15
    float acc[16];
    const float bias = bl[col];
    #pragma unroll
    for (int i = 0; i < 16; ++i) acc[i] = bias;

    for (int k = 0; k < 128; ++k) {
        float wl = Wl[k * 128 + col];
        float wr = Wr[k * 128 + col];
        #pragma unroll
        for (int i = 0; i < 16; ++i) {
            int r = half * 16 + i;
            acc[i] = fmaf(Am[r][k], wl, fmaf(Ax[r][k], wr, acc[i]));
        }
    }

    #pragma unroll
    for (int i = 0; i < 16; ++i) {
        int row = rb + half * 16 + i;
        if (row < nrows) xout[(size_t)row * D + col] = fmaxf(acc[i], 0.0f);
    }
}

// ---------------- classifier: out = relu(x2g@Wc1+bc1) @ Wc2 + bc2 ----------------
__global__ __launch_bounds__(256) void classifier_k(
    const float* __restrict__ x2g,
    const float* __restrict__ Wc1, const float* __restrict__ bc1,
    const float* __restrict__ Wc2, const float* __restrict__ bc2,
    float* __restrict__ out, int nrows) {
    __shared__ float Xs[32][128];
    __shared__ float Hs[32][128];
    const int rb = blockIdx.x * 32;
    const int t  = threadIdx.x;

    #pragma unroll
    for (int it = 0; it < 4; ++it) {
        int j  = t + it * 256;
        int r  = j >> 5;
        int k4 = j & 31;
        int row = rb + r;
        float4 v = make_float4(0.f, 0.f, 0.f, 0.f);
        if (row < nrows) v = *reinterpret_cast<const float4*>(x2g + (size_t)row * D + k4 * 4);
        *reinterpret_cast<float4*>(&Xs[r][k4 * 4]) = v;
    }
    __syncthreads();

    {
        const int col  = t & 127;
        const int half = t >> 7;
        float acc[16];
        const float bias = bc1[col];
        #pragma unroll
        for (int i = 0; i < 16; ++i) acc[i] = bias;
        for (int k = 0; k < 128; ++k) {
            float w = Wc1[k * 128 + col];
            #pragma unroll
            for (int i = 0; i < 16; ++i)
                acc[i] = fmaf(Xs[half * 16 + i][k], w, acc[i]);
        }
        #pragma unroll
        for (int i = 0; i < 16; ++i)
            Hs[half * 16 + i][col] = fmaxf(acc[i], 0.0f);
    }
    __syncthreads();

    {
        const int c  = t & 31;   // class
        const int rg = t >> 5;   // 0..7; rows rg, rg+8, rg+16, rg+24
        float o[4];
        const float b2 = bc2[c];
        #pragma unroll
        for (int i = 0; i < 4; ++i) o[i] = b2;
        for (int k = 0; k < 128; ++k) {
            float w = Wc2[k * 32 + c];
            #pragma unroll
            for (int i = 0; i < 4; ++i)
                o[i] = fmaf(Hs[rg + 8 * i][k], w, o[i]);
        }
        #pragma unroll
        for (int i = 0; i < 4; ++i) {
            int row = rb + rg + 8 * i;
            if (row < nrows) out[(size_t)row * C + c] = o[i];
        }
    }
}

// ---------------- launch ----------------

extern "C" void kernel_launch(void* const* d_in, const int* in_sizes, int n_in,
                              void* d_out, int out_size, void* d_ws, size_t ws_size,
                              hipStream_t stream) {
    const float* node_state = (const float*)d_in[0];
    const int*   edge_index = (const int*)d_in[1];
    const int*   label_pos  = (const int*)d_in[2];
    const float* W1l = (const float*)d_in[3];
    const float* b1l = (const float*)d_in[4];
    const float* W1r = (const float*)d_in[5];
    const float* W2l = (const float*)d_in[6];
    const float* b2l = (const float*)d_in[7];
    const float* W2r = (const float*)d_in[8];
    const float* Wc1 = (const float*)d_in[9];
    const float* bc1 = (const float*)d_in[10];
    const float* Wc2 = (const float*)d_in[11];
    const float* bc2 = (const float*)d_in[12];
    float* out = (float*)d_out;

    const int* src = edge_index;       // edge_index[0]
    const int* dst = edge_index + E;   // edge_index[1]

    // workspace layout
    char* ws = (char*)d_ws;
    int* deg     = (int*)ws;                     ws += sizeof(int) * N;
    int* roff    = (int*)ws;                     ws += sizeof(int) * (N + 1);
    int* cur     = (int*)ws;                     ws += sizeof(int) * N;
    int* csr_src = (int*)ws;                     ws += sizeof(int) * E;
    float* bufA  = (float*)ws;                   ws += sizeof(float) * (size_t)N * D;
    float* x1    = (float*)ws;                   ws += sizeof(float) * (size_t)N * D;
    // bufA serves as: mean1 [N][D] for layer 1, then mean2g [B][D] + x2g [B][D]
    float* mean1  = bufA;
    float* mean2g = bufA;
    float* x2g    = bufA + (size_t)B * D;
    // total: ~3.6 MB ints + 102.4 MB floats ≈ 106 MB

    const int TB = 256;

    // ---- CSR build (pull formulation; kills fp32 atomics) ----
    hipMemsetAsync(deg, 0, sizeof(int) * N, stream);
    deg_k<<<(E + TB - 1) / TB, TB, 0, stream>>>(dst, deg, E);
    scan_k<<<1, 1024, 0, stream>>>(deg, roff, cur, N);
    fill_k<<<(E + TB - 1) / TB, TB, 0, stream>>>(src, dst, cur, csr_src, E);

    // ---- layer 1 ----
    gather_mean_k<false><<<(N + 3) / 4, TB, 0, stream>>>(
        node_state, roff, csr_src, nullptr, mean1, N);
    sage_gemm_k<false><<<(N + 31) / 32, TB, 0, stream>>>(
        mean1, node_state, nullptr, W1l, b1l, W1r, x1, N);

    // ---- layer 2 (only label rows need aggregation/output) ----
    gather_mean_k<true><<<(B + 3) / 4, TB, 0, stream>>>(
        x1, roff, csr_src, label_pos, mean2g, B);
    sage_gemm_k<true><<<(B + 31) / 32, TB, 0, stream>>>(
        mean2g, x1, label_pos, W2l, b2l, W2r, x2g, B);

    // ---- classifier ----
    classifier_k<<<(B + 31) / 32, TB, 0, stream>>>(x2g, Wc1, bc1, Wc2, bc2, out, B);
}

// Round 3
// 513.242 us; speedup vs baseline: 4.8023x; 1.4318x over previous
//
#include <hip/hip_runtime.h>
#include <hip/hip_bf16.h>

// Problem constants (match reference setup_inputs)
static constexpr int N = 100000;
static constexpr int E = 600000;
static constexpr int D = 128;
static constexpr int B = 10000;
static constexpr int C = 32;

// ---------------- CSR build ----------------

__global__ void deg_k(const int* __restrict__ dst, int* __restrict__ deg, int nE) {
    int i = blockIdx.x * blockDim.x + threadIdx.x;
    if (i < nE) atomicAdd(&deg[dst[i]], 1);
}

// phase 1: per-block (1024 elems) sums
__global__ __launch_bounds__(256) void scan1_k(const int* __restrict__ deg,
                                               int* __restrict__ bsum, int n) {
    __shared__ int lsum[256];
    const int t = threadIdx.x;
    const int base = blockIdx.x * 1024 + t * 4;
    int s = 0;
    #pragma unroll
    for (int i = 0; i < 4; ++i) {
        int idx = base + i;
        if (idx < n) s += deg[idx];
    }
    lsum[t] = s;
    __syncthreads();
    for (int off = 128; off > 0; off >>= 1) {
        if (t < off) lsum[t] += lsum[t + off];
        __syncthreads();
    }
    if (t == 0) bsum[blockIdx.x] = lsum[0];
}

// phase 2: single tiny block scans the <=128 block sums; writes roff[n]=total
__global__ __launch_bounds__(128) void scan2_k(const int* __restrict__ bsum,
                                               int* __restrict__ boff,
                                               int* __restrict__ roff, int nb, int n) {
    __shared__ int s[128];
    const int t = threadIdx.x;
    const int v = (t < nb) ? bsum[t] : 0;
    s[t] = v;
    __syncthreads();
    for (int off = 1; off < 128; off <<= 1) {
        int u = (t >= off) ? s[t - off] : 0;
        __syncthreads();
        s[t] += u;
        __syncthreads();
    }
    if (t < nb) boff[t] = s[t] - v;       // exclusive
    if (t == 127) roff[n] = s[127];       // total
}

// phase 3: re-scan each 1024-chunk with its block offset; write roff & cur
__global__ __launch_bounds__(256) void scan3_k(const int* __restrict__ deg,
                                               const int* __restrict__ boff,
                                               int* __restrict__ roff,
                                               int* __restrict__ cur, int n) {
    __shared__ int lsum[256];
    const int t = threadIdx.x;
    const int base = blockIdx.x * 1024 + t * 4;
    int d[4];
    int s = 0;
    #pragma unroll
    for (int i = 0; i < 4; ++i) {
        int idx = base + i;
        d[i] = (idx < n) ? deg[idx] : 0;
        s += d[i];
    }
    lsum[t] = s;
    __syncthreads();
    for (int off = 1; off < 256; off <<= 1) {
        int u = (t >= off) ? lsum[t - off] : 0;
        __syncthreads();
        lsum[t] += u;
        __syncthreads();
    }
    int run = boff[blockIdx.x] + lsum[t] - s;   // exclusive prefix of this thread
    #pragma unroll
    for (int i = 0; i < 4; ++i) {
        int idx = base + i;
        if (idx < n) {
            roff[idx] = run;
            cur[idx]  = run;
            run += d[i];
        }
    }
}

__global__ void fill_k(const int* __restrict__ src, const int* __restrict__ dst,
                       int* __restrict__ cur, int* __restrict__ csr_src, int nE) {
    int e = blockIdx.x * blockDim.x + threadIdx.x;
    if (e < nE) {
        int p = atomicAdd(&cur[dst[e]], 1);
        csr_src[p] = src[e];
    }
}

// ---------------- gather-mean aggregation ----------------
// one wave (64 lanes) per output row; lane handles 2 floats (float2) of D=128.
template <bool GATHER>
__global__ __launch_bounds__(256) void gather_mean_k(
    const float* __restrict__ x, const int* __restrict__ roff,
    const int* __restrict__ csr_src, const int* __restrict__ rows,
    float* __restrict__ out, int nrows) {
    const int w = blockIdx.x * (blockDim.x >> 6) + (threadIdx.x >> 6);
    if (w >= nrows) return;
    const int lane = threadIdx.x & 63;
    const int n  = GATHER ? rows[w] : w;
    const int jb = roff[n];
    const int je = roff[n + 1];
    const float* xb = x + lane * 2;

    float ax = 0.f, ay = 0.f;
    int j = jb;
    for (; j + 4 <= je; j += 4) {
        int s0 = csr_src[j + 0];
        int s1 = csr_src[j + 1];
        int s2 = csr_src[j + 2];
        int s3 = csr_src[j + 3];
        float2 v0 = *reinterpret_cast<const float2*>(xb + (size_t)s0 * D);
        float2 v1 = *reinterpret_cast<const float2*>(xb + (size_t)s1 * D);
        float2 v2 = *reinterpret_cast<const float2*>(xb + (size_t)s2 * D);
        float2 v3 = *reinterpret_cast<const float2*>(xb + (size_t)s3 * D);
        ax += v0.x + v1.x + v2.x + v3.x;
        ay += v0.y + v1.y + v2.y + v3.y;
    }
    for (; j < je; ++j) {
        int s = csr_src[j];
        float2 v = *reinterpret_cast<const float2*>(xb + (size_t)s * D);
        ax += v.x;
        ay += v.y;
    }
    const float inv = 1.0f / fmaxf((float)(je - jb), 1.0f);
    *reinterpret_cast<float2*>(out + (size_t)w * D + lane * 2) =
        make_float2(ax * inv, ay * inv);
}

// ---------------- SAGE layer GEMM ----------------
template <bool GATHER>
__global__ __launch_bounds__(256) void sage_gemm_k(
    const float* __restrict__ mean, const float* __restrict__ xin,
    const int* __restrict__ rows,
    const float* __restrict__ Wl, const float* __restrict__ bl,
    const float* __restrict__ Wr, float* __restrict__ xout, int nrows) {
    __shared__ float Am[32][128];
    __shared__ float Ax[32][128];
    const int rb = blockIdx.x * 32;
    const int t  = threadIdx.x;

    #pragma unroll
    for (int it = 0; it < 4; ++it) {
        int j  = t + it * 256;   // float4 index within tile, 0..1023
        int r  = j >> 5;         // 0..31
        int k4 = j & 31;         // 0..31
        int row = rb + r;
        float4 a4 = make_float4(0.f, 0.f, 0.f, 0.f);
        float4 x4 = make_float4(0.f, 0.f, 0.f, 0.f);
        if (row < nrows) {
            int grow = GATHER ? rows[row] : row;
            a4 = *reinterpret_cast<const float4*>(mean + (size_t)row * D + k4 * 4);
            x4 = *reinterpret_cast<const float4*>(xin + (size_t)grow * D + k4 * 4);
        }
        *reinterpret_cast<float4*>(&Am[r][k4 * 4]) = a4;
        *reinterpret_cast<float4*>(&Ax[r][k4 * 4]) = x4;
    }
    __syncthreads();

    const int col  = t & 127;
    const int half = t >> 7;  // 0 or 1: rows half*16 .. half*16+15
    float acc[16];
    const float bias = bl[col];
    #pragma unroll
    for (int i = 0; i < 16; ++i) acc[i] = bias;

    for (int k = 0; k < 128; ++k) {
        float wl = Wl[k * 128 + col];
        float wr = Wr[k * 128 + col];
        #pragma unroll
        for (int i = 0; i < 16; ++i) {
            int r = half * 16 + i;
            acc[i] = fmaf(Am[r][k], wl, fmaf(Ax[r][k], wr, acc[i]));
        }
    }

    #pragma unroll
    for (int i = 0; i < 16; ++i) {
        int row = rb + half * 16 + i;
        if (row < nrows) xout[(size_t)row * D + col] = fmaxf(acc[i], 0.0f);
    }
}

// ---------------- classifier: out = relu(x2g@Wc1+bc1) @ Wc2 + bc2 ----------------
__global__ __launch_bounds__(256) void classifier_k(
    const float* __restrict__ x2g,
    const float* __restrict__ Wc1, const float* __restrict__ bc1,
    const float* __restrict__ Wc2, const float* __restrict__ bc2,
    float* __restrict__ out, int nrows) {
    __shared__ float Xs[32][128];
    __shared__ float Hs[32][128];
    const int rb = blockIdx.x * 32;
    const int t  = threadIdx.x;

    #pragma unroll
    for (int it = 0; it < 4; ++it) {
        int j  = t + it * 256;
        int r  = j >> 5;
        int k4 = j & 31;
        int row = rb + r;
        float4 v = make_float4(0.f, 0.f, 0.f, 0.f);
        if (row < nrows) v = *reinterpret_cast<const float4*>(x2g + (size_t)row * D + k4 * 4);
        *reinterpret_cast<float4*>(&Xs[r][k4 * 4]) = v;
    }
    __syncthreads();

    {
        const int col  = t & 127;
        const int half = t >> 7;
        float acc[16];
        const float bias = bc1[col];
        #pragma unroll
        for (int i = 0; i < 16; ++i) acc[i] = bias;
        for (int k = 0; k < 128; ++k) {
            float w = Wc1[k * 128 + col];
            #pragma unroll
            for (int i = 0; i < 16; ++i)
                acc[i] = fmaf(Xs[half * 16 + i][k], w, acc[i]);
        }
        #pragma unroll
        for (int i = 0; i < 16; ++i)
            Hs[half * 16 + i][col] = fmaxf(acc[i], 0.0f);
    }
    __syncthreads();

    {
        const int c  = t & 31;   // class
        const int rg = t >> 5;   // 0..7; rows rg, rg+8, rg+16, rg+24
        float o[4];
        const float b2 = bc2[c];
        #pragma unroll
        for (int i = 0; i < 4; ++i) o[i] = b2;
        for (int k = 0; k < 128; ++k) {
            float w = Wc2[k * 32 + c];
            #pragma unroll
            for (int i = 0; i < 4; ++i)
                o[i] = fmaf(Hs[rg + 8 * i][k], w, o[i]);
        }
        #pragma unroll
        for (int i = 0; i < 4; ++i) {
            int row = rb + rg + 8 * i;
            if (row < nrows) out[(size_t)row * C + c] = o[i];
        }
    }
}

// ---------------- launch ----------------

extern "C" void kernel_launch(void* const* d_in, const int* in_sizes, int n_in,
                              void* d_out, int out_size, void* d_ws, size_t ws_size,
                              hipStream_t stream) {
    const float* node_state = (const float*)d_in[0];
    const int*   edge_index = (const int*)d_in[1];
    const int*   label_pos  = (const int*)d_in[2];
    const float* W1l = (const float*)d_in[3];
    const float* b1l = (const float*)d_in[4];
    const float* W1r = (const float*)d_in[5];
    const float* W2l = (const float*)d_in[6];
    const float* b2l = (const float*)d_in[7];
    const float* W2r = (const float*)d_in[8];
    const float* Wc1 = (const float*)d_in[9];
    const float* bc1 = (const float*)d_in[10];
    const float* Wc2 = (const float*)d_in[11];
    const float* bc2 = (const float*)d_in[12];
    float* out = (float*)d_out;

    const int* src = edge_index;       // edge_index[0]
    const int* dst = edge_index + E;   // edge_index[1]

    // workspace layout
    char* ws = (char*)d_ws;
    int* deg     = (int*)ws;                     ws += sizeof(int) * N;
    int* roff    = (int*)ws;                     ws += sizeof(int) * (N + 1);
    int* cur     = (int*)ws;                     ws += sizeof(int) * N;
    int* csr_src = (int*)ws;                     ws += sizeof(int) * E;
    int* bsum    = (int*)ws;                     ws += sizeof(int) * 128;
    int* boff    = (int*)ws;                     ws += sizeof(int) * 128;
    float* bufA  = (float*)ws;                   ws += sizeof(float) * (size_t)N * D;
    float* x1    = (float*)ws;                   ws += sizeof(float) * (size_t)N * D;
    // bufA serves as: mean1 [N][D] for layer 1, then mean2g [B][D] + x2g [B][D]
    float* mean1  = bufA;
    float* mean2g = bufA;
    float* x2g    = bufA + (size_t)B * D;

    const int TB = 256;
    const int NB = (N + 1023) / 1024;   // 98 scan blocks

    // ---- CSR build (pull formulation; no fp32 atomics) ----
    hipMemsetAsync(deg, 0, sizeof(int) * N, stream);
    deg_k<<<(E + TB - 1) / TB, TB, 0, stream>>>(dst, deg, E);
    scan1_k<<<NB, 256, 0, stream>>>(deg, bsum, N);
    scan2_k<<<1, 128, 0, stream>>>(bsum, boff, roff, NB, N);
    scan3_k<<<NB, 256, 0, stream>>>(deg, boff, roff, cur, N);
    fill_k<<<(E + TB - 1) / TB, TB, 0, stream>>>(src, dst, cur, csr_src, E);

    // ---- layer 1 ----
    gather_mean_k<false><<<(N + 3) / 4, TB, 0, stream>>>(
        node_state, roff, csr_src, nullptr, mean1, N);
    sage_gemm_k<false><<<(N + 31) / 32, TB, 0, stream>>>(
        mean1, node_state, nullptr, W1l, b1l, W1r, x1, N);

    // ---- layer 2 (only label rows need aggregation/output) ----
    gather_mean_k<true><<<(B + 3) / 4, TB, 0, stream>>>(
        x1, roff, csr_src, label_pos, mean2g, B);
    sage_gemm_k<true><<<(B + 31) / 32, TB, 0, stream>>>(
        mean2g, x1, label_pos, W2l, b2l, W2r, x2g, B);

    // ---- classifier ----
    classifier_k<<<(B + 31) / 32, TB, 0, stream>>>(x2g, Wc1, bc1, Wc2, bc2, out, B);
}

// Round 4
// 392.840 us; speedup vs baseline: 6.2741x; 1.3065x over previous
//
#include <hip/hip_runtime.h>
#include <hip/hip_bf16.h>

// Problem constants (match reference setup_inputs)
static constexpr int N = 100000;
static constexpr int E = 600000;
static constexpr int D = 128;
static constexpr int B = 10000;
static constexpr int C = 32;

typedef __attribute__((ext_vector_type(8))) short short8;   // 8 bf16 (4 VGPRs)
typedef __attribute__((ext_vector_type(4))) float f32x4;    // MFMA acc

// bf16 RNE helpers (bit-level, no NaN inputs here)
static __device__ __forceinline__ unsigned short f2bf(float f) {
    unsigned u = __float_as_uint(f);
    unsigned r = (u + 0x7FFFu + ((u >> 16) & 1u)) >> 16;
    return (unsigned short)r;
}
static __device__ __forceinline__ float bf2f(unsigned short h) {
    return __uint_as_float(((unsigned)h) << 16);
}

// ---------------- CSR build ----------------

__global__ void deg_k(const int* __restrict__ dst, int* __restrict__ deg, int nE) {
    int i = blockIdx.x * blockDim.x + threadIdx.x;
    if (i < nE) atomicAdd(&deg[dst[i]], 1);
}

__global__ __launch_bounds__(256) void scan1_k(const int* __restrict__ deg,
                                               int* __restrict__ bsum, int n) {
    __shared__ int lsum[256];
    const int t = threadIdx.x;
    const int base = blockIdx.x * 1024 + t * 4;
    int s = 0;
    #pragma unroll
    for (int i = 0; i < 4; ++i) {
        int idx = base + i;
        if (idx < n) s += deg[idx];
    }
    lsum[t] = s;
    __syncthreads();
    for (int off = 128; off > 0; off >>= 1) {
        if (t < off) lsum[t] += lsum[t + off];
        __syncthreads();
    }
    if (t == 0) bsum[blockIdx.x] = lsum[0];
}

__global__ __launch_bounds__(128) void scan2_k(const int* __restrict__ bsum,
                                               int* __restrict__ boff,
                                               int* __restrict__ roff, int nb, int n) {
    __shared__ int s[128];
    const int t = threadIdx.x;
    const int v = (t < nb) ? bsum[t] : 0;
    s[t] = v;
    __syncthreads();
    for (int off = 1; off < 128; off <<= 1) {
        int u = (t >= off) ? s[t - off] : 0;
        __syncthreads();
        s[t] += u;
        __syncthreads();
    }
    if (t < nb) boff[t] = s[t] - v;
    if (t == 127) roff[n] = s[127];
}

__global__ __launch_bounds__(256) void scan3_k(const int* __restrict__ deg,
                                               const int* __restrict__ boff,
                                               int* __restrict__ roff,
                                               int* __restrict__ cur, int n) {
    __shared__ int lsum[256];
    const int t = threadIdx.x;
    const int base = blockIdx.x * 1024 + t * 4;
    int d[4];
    int s = 0;
    #pragma unroll
    for (int i = 0; i < 4; ++i) {
        int idx = base + i;
        d[i] = (idx < n) ? deg[idx] : 0;
        s += d[i];
    }
    lsum[t] = s;
    __syncthreads();
    for (int off = 1; off < 256; off <<= 1) {
        int u = (t >= off) ? lsum[t - off] : 0;
        __syncthreads();
        lsum[t] += u;
        __syncthreads();
    }
    int run = boff[blockIdx.x] + lsum[t] - s;
    #pragma unroll
    for (int i = 0; i < 4; ++i) {
        int idx = base + i;
        if (idx < n) {
            roff[idx] = run;
            cur[idx]  = run;
            run += d[i];
        }
    }
}

__global__ void fill_k(const int* __restrict__ src, const int* __restrict__ dst,
                       int* __restrict__ cur, int* __restrict__ csr_src, int nE) {
    int e = blockIdx.x * blockDim.x + threadIdx.x;
    if (e < nE) {
        int p = atomicAdd(&cur[dst[e]], 1);
        csr_src[p] = src[e];
    }
}

// ---------------- weight swizzle: fp32 W[128][128] -> MFMA-B fragment order, hi/lo bf16 ----------------
// per matrix: out[plane][((ko*8+no)*64+lane)*8+j], value = W[ko*32+(lane>>4)*8+j][no*16+(lane&15)]
__global__ __launch_bounds__(256) void swz_k(const float* W0, const float* W1,
                                             const float* W2, const float* W3,
                                             unsigned short* __restrict__ out) {
    const float* W = (blockIdx.x == 0) ? W0 : (blockIdx.x == 1) ? W1
                   : (blockIdx.x == 2) ? W2 : W3;
    unsigned short* o = out + (size_t)blockIdx.x * 32768;
    #pragma unroll
    for (int it = 0; it < 64; ++it) {
        int f = threadIdx.x + it * 256;          // 0..16383
        int j = f & 7;
        int lane = (f >> 3) & 63;
        int fi = f >> 9;                         // 0..31 = ko*8+no
        int k = (fi >> 3) * 32 + (lane >> 4) * 8 + j;
        int n = (fi & 7) * 16 + (lane & 15);
        float a = W[k * 128 + n];
        unsigned short h = f2bf(a);
        unsigned short l = f2bf(a - bf2f(h));
        o[f] = h;
        o[16384 + f] = l;
    }
}

// ---------------- gather-mean aggregation (unchanged) ----------------
template <bool GATHER>
__global__ __launch_bounds__(256) void gather_mean_k(
    const float* __restrict__ x, const int* __restrict__ roff,
    const int* __restrict__ csr_src, const int* __restrict__ rows,
    float* __restrict__ out, int nrows) {
    const int w = blockIdx.x * (blockDim.x >> 6) + (threadIdx.x >> 6);
    if (w >= nrows) return;
    const int lane = threadIdx.x & 63;
    const int n  = GATHER ? rows[w] : w;
    const int jb = roff[n];
    const int je = roff[n + 1];
    const float* xb = x + lane * 2;

    float ax = 0.f, ay = 0.f;
    int j = jb;
    for (; j + 4 <= je; j += 4) {
        int s0 = csr_src[j + 0];
        int s1 = csr_src[j + 1];
        int s2 = csr_src[j + 2];
        int s3 = csr_src[j + 3];
        float2 v0 = *reinterpret_cast<const float2*>(xb + (size_t)s0 * D);
        float2 v1 = *reinterpret_cast<const float2*>(xb + (size_t)s1 * D);
        float2 v2 = *reinterpret_cast<const float2*>(xb + (size_t)s2 * D);
        float2 v3 = *reinterpret_cast<const float2*>(xb + (size_t)s3 * D);
        ax += v0.x + v1.x + v2.x + v3.x;
        ay += v0.y + v1.y + v2.y + v3.y;
    }
    for (; j < je; ++j) {
        int s = csr_src[j];
        float2 v = *reinterpret_cast<const float2*>(xb + (size_t)s * D);
        ax += v.x;
        ay += v.y;
    }
    const float inv = 1.0f / fmaxf((float)(je - jb), 1.0f);
    *reinterpret_cast<float2*>(out + (size_t)w * D + lane * 2) =
        make_float2(ax * inv, ay * inv);
}

// ---------------- SAGE layer, split-bf16 MFMA ----------------
// xout[row] = relu( mean[row]@Wl + bl + xin[grow]@Wr ), fp32-accurate via
// A@W ~= Ah@Wh + Al@Wh + Ah@Wl   (3-term hi/lo split, residual ~2^-18)
// Block: 128 rows x 128 cols, 4 waves (each 32 rows x 128 cols).
// K chunked at 64 per branch; W pre-swizzled in fragment order (hi plane then lo).
template <bool GATHER>
__global__ __launch_bounds__(256) void sage_mfma_k(
    const float* __restrict__ mean, const float* __restrict__ xin,
    const int* __restrict__ rows,
    const unsigned short* __restrict__ WlSw, const unsigned short* __restrict__ WrSw,
    const float* __restrict__ bl, float* __restrict__ xout, int nrows)
{
    __shared__ alignas(16) unsigned short Ah[128 * 72];  // rows x (64k + 8 pad)
    __shared__ alignas(16) unsigned short Al[128 * 72];
    __shared__ alignas(16) unsigned short Bs[8192];      // one plane, one 64-k chunk

    const int t = threadIdx.x;
    const int w = t >> 6;
    const int lane = t & 63;
    const int mcol = lane & 15;
    const int q = lane >> 4;
    const int rb = blockIdx.x * 128;

    f32x4 acc[2][8];
    #pragma unroll
    for (int mt = 0; mt < 2; ++mt)
        #pragma unroll
        for (int no = 0; no < 8; ++no)
            acc[mt][no] = (f32x4){0.f, 0.f, 0.f, 0.f};

    for (int br = 0; br < 2; ++br) {
        const unsigned short* Wm = br ? WrSw : WlSw;
        for (int kc = 0; kc < 2; ++kc) {
            __syncthreads();   // protect LDS from prior phase readers
            // ---- stage A chunk (128 rows x 64 k), fp32 -> hi/lo bf16
            #pragma unroll
            for (int it = 0; it < 8; ++it) {
                int f = t + it * 256;          // 0..2047
                int row = f >> 4;
                int k4 = f & 15;
                int gr = rb + row;
                float4 v = make_float4(0.f, 0.f, 0.f, 0.f);
                if (gr < nrows) {
                    if (br == 0) {
                        v = *reinterpret_cast<const float4*>(
                                mean + (size_t)gr * D + kc * 64 + k4 * 4);
                    } else {
                        int g = GATHER ? rows[gr] : gr;
                        v = *reinterpret_cast<const float4*>(
                                xin + (size_t)g * D + kc * 64 + k4 * 4);
                    }
                }
                ushort4 h, l;
                h.x = f2bf(v.x); l.x = f2bf(v.x - bf2f(h.x));
                h.y = f2bf(v.y); l.y = f2bf(v.y - bf2f(h.y));
                h.z = f2bf(v.z); l.z = f2bf(v.z - bf2f(h.z));
                h.w = f2bf(v.w); l.w = f2bf(v.w - bf2f(h.w));
                *reinterpret_cast<ushort4*>(&Ah[row * 72 + k4 * 4]) = h;
                *reinterpret_cast<ushort4*>(&Al[row * 72 + k4 * 4]) = l;
            }
            // ---- stage B: hi plane chunk (16 KB copy)
            {
                const uint4* s = reinterpret_cast<const uint4*>(Wm + kc * 8192);
                uint4* d = reinterpret_cast<uint4*>(Bs);
                #pragma unroll
                for (int it = 0; it < 4; ++it) d[t + it * 256] = s[t + it * 256];
            }
            __syncthreads();
            // ---- A fragments -> registers (kept across both B sub-phases)
            short8 aH[2][2], aL[2][2];   // [kp][mt]
            #pragma unroll
            for (int kp = 0; kp < 2; ++kp)
                #pragma unroll
                for (int mt = 0; mt < 2; ++mt) {
                    int rloc = w * 32 + mt * 16 + mcol;
                    aH[kp][mt] = *reinterpret_cast<const short8*>(
                        &Ah[rloc * 72 + kp * 32 + q * 8]);
                    aL[kp][mt] = *reinterpret_cast<const short8*>(
                        &Al[rloc * 72 + kp * 32 + q * 8]);
                }
            // ---- MFMA: Ah*Bh + Al*Bh
            #pragma unroll
            for (int no = 0; no < 8; ++no)
                #pragma unroll
                for (int kp = 0; kp < 2; ++kp) {
                    short8 b = *reinterpret_cast<const short8*>(
                        &Bs[((kp * 8 + no) * 64 + lane) * 8]);
                    #pragma unroll
                    for (int mt = 0; mt < 2; ++mt) {
                        acc[mt][no] = __builtin_amdgcn_mfma_f32_16x16x32_bf16(
                            aH[kp][mt], b, acc[mt][no], 0, 0, 0);
                        acc[mt][no] = __builtin_amdgcn_mfma_f32_16x16x32_bf16(
                            aL[kp][mt], b, acc[mt][no], 0, 0, 0);
                    }
                }
            __syncthreads();
            // ---- stage B: lo plane chunk
            {
                const uint4* s = reinterpret_cast<const uint4*>(Wm + 16384 + kc * 8192);
                uint4* d = reinterpret_cast<uint4*>(Bs);
                #pragma unroll
                for (int it = 0; it < 4; ++it) d[t + it * 256] = s[t + it * 256];
            }
            __syncthreads();
            // ---- MFMA: Ah*Bl
            #pragma unroll
            for (int no = 0; no < 8; ++no)
                #pragma unroll
                for (int kp = 0; kp < 2; ++kp) {
                    short8 b = *reinterpret_cast<const short8*>(
                        &Bs[((kp * 8 + no) * 64 + lane) * 8]);
                    #pragma unroll
                    for (int mt = 0; mt < 2; ++mt)
                        acc[mt][no] = __builtin_amdgcn_mfma_f32_16x16x32_bf16(
                            aH[kp][mt], b, acc[mt][no], 0, 0, 0);
                }
        }
    }
    // ---- epilogue: bias + relu + store (C/D layout: col=lane&15, row=q*4+reg)
    #pragma unroll
    for (int no = 0; no < 8; ++no) {
        int col = no * 16 + mcol;
        float bias = bl[col];
        #pragma unroll
        for (int mt = 0; mt < 2; ++mt) {
            #pragma unroll
            for (int r = 0; r < 4; ++r) {
                int row = rb + w * 32 + mt * 16 + q * 4 + r;
                if (row < nrows)
                    xout[(size_t)row * D + col] = fmaxf(acc[mt][no][r] + bias, 0.f);
            }
        }
    }
}

// ---------------- classifier: out = relu(x2g@Wc1+bc1) @ Wc2 + bc2 ----------------
__global__ __launch_bounds__(256) void classifier_k(
    const float* __restrict__ x2g,
    const float* __restrict__ Wc1, const float* __restrict__ bc1,
    const float* __restrict__ Wc2, const float* __restrict__ bc2,
    float* __restrict__ out, int nrows) {
    __shared__ float Xs[32][128];
    __shared__ float Hs[32][128];
    const int rb = blockIdx.x * 32;
    const int t  = threadIdx.x;

    #pragma unroll
    for (int it = 0; it < 4; ++it) {
        int j  = t + it * 256;
        int r  = j >> 5;
        int k4 = j & 31;
        int row = rb + r;
        float4 v = make_float4(0.f, 0.f, 0.f, 0.f);
        if (row < nrows) v = *reinterpret_cast<const float4*>(x2g + (size_t)row * D + k4 * 4);
        *reinterpret_cast<float4*>(&Xs[r][k4 * 4]) = v;
    }
    __syncthreads();

    {
        const int col  = t & 127;
        const int half = t >> 7;
        float acc[16];
        const float bias = bc1[col];
        #pragma unroll
        for (int i = 0; i < 16; ++i) acc[i] = bias;
        for (int k = 0; k < 128; ++k) {
            float w = Wc1[k * 128 + col];
            #pragma unroll
            for (int i = 0; i < 16; ++i)
                acc[i] = fmaf(Xs[half * 16 + i][k], w, acc[i]);
        }
        #pragma unroll
        for (int i = 0; i < 16; ++i)
            Hs[half * 16 + i][col] = fmaxf(acc[i], 0.0f);
    }
    __syncthreads();

    {
        const int c  = t & 31;
        const int rg = t >> 5;
        float o[4];
        const float b2 = bc2[c];
        #pragma unroll
        for (int i = 0; i < 4; ++i) o[i] = b2;
        for (int k = 0; k < 128; ++k) {
            float w = Wc2[k * 32 + c];
            #pragma unroll
            for (int i = 0; i < 4; ++i)
                o[i] = fmaf(Hs[rg + 8 * i][k], w, o[i]);
        }
        #pragma unroll
        for (int i = 0; i < 4; ++i) {
            int row = rb + rg + 8 * i;
            if (row < nrows) out[(size_t)row * C + c] = o[i];
        }
    }
}

// ---------------- launch ----------------

extern "C" void kernel_launch(void* const* d_in, const int* in_sizes, int n_in,
                              void* d_out, int out_size, void* d_ws, size_t ws_size,
                              hipStream_t stream) {
    const float* node_state = (const float*)d_in[0];
    const int*   edge_index = (const int*)d_in[1];
    const int*   label_pos  = (const int*)d_in[2];
    const float* W1l = (const float*)d_in[3];
    const float* b1l = (const float*)d_in[4];
    const float* W1r = (const float*)d_in[5];
    const float* W2l = (const float*)d_in[6];
    const float* b2l = (const float*)d_in[7];
    const float* W2r = (const float*)d_in[8];
    const float* Wc1 = (const float*)d_in[9];
    const float* bc1 = (const float*)d_in[10];
    const float* Wc2 = (const float*)d_in[11];
    const float* bc2 = (const float*)d_in[12];
    float* out = (float*)d_out;

    const int* src = edge_index;       // edge_index[0]
    const int* dst = edge_index + E;   // edge_index[1]

    // workspace layout (floats first for alignment)
    char* ws = (char*)d_ws;
    float* bufA  = (float*)ws;                    ws += sizeof(float) * (size_t)N * D;
    float* x1    = (float*)ws;                    ws += sizeof(float) * (size_t)N * D;
    unsigned short* Wsw = (unsigned short*)ws;    ws += sizeof(unsigned short) * 4 * 32768;
    int* deg     = (int*)ws;                      ws += sizeof(int) * N;
    int* roff    = (int*)ws;                      ws += sizeof(int) * (N + 1);
    int* cur     = (int*)ws;                      ws += sizeof(int) * N;
    int* csr_src = (int*)ws;                      ws += sizeof(int) * E;
    int* bsum    = (int*)ws;                      ws += sizeof(int) * 128;
    int* boff    = (int*)ws;                      ws += sizeof(int) * 128;
    // bufA: mean1 [N][D] for layer 1; then mean2g [B][D] + x2g [B][D]
    float* mean1  = bufA;
    float* mean2g = bufA;
    float* x2g    = bufA + (size_t)B * D;

    const int TB = 256;
    const int NB = (N + 1023) / 1024;

    // ---- CSR build ----
    hipMemsetAsync(deg, 0, sizeof(int) * N, stream);
    deg_k<<<(E + TB - 1) / TB, TB, 0, stream>>>(dst, deg, E);
    scan1_k<<<NB, 256, 0, stream>>>(deg, bsum, N);
    scan2_k<<<1, 128, 0, stream>>>(bsum, boff, roff, NB, N);
    scan3_k<<<NB, 256, 0, stream>>>(deg, boff, roff, cur, N);
    fill_k<<<(E + TB - 1) / TB, TB, 0, stream>>>(src, dst, cur, csr_src, E);

    // ---- weight swizzle (W1l, W1r, W2l, W2r) ----
    swz_k<<<4, 256, 0, stream>>>(W1l, W1r, W2l, W2r, Wsw);

    // ---- layer 1 ----
    gather_mean_k<false><<<(N + 3) / 4, TB, 0, stream>>>(
        node_state, roff, csr_src, nullptr, mean1, N);
    sage_mfma_k<false><<<(N + 127) / 128, TB, 0, stream>>>(
        mean1, node_state, nullptr, Wsw, Wsw + 32768, b1l, x1, N);

    // ---- layer 2 (only label rows) ----
    gather_mean_k<true><<<(B + 3) / 4, TB, 0, stream>>>(
        x1, roff, csr_src, label_pos, mean2g, B);
    sage_mfma_k<true><<<(B + 127) / 128, TB, 0, stream>>>(
        mean2g, x1, label_pos, Wsw + 65536, Wsw + 98304, b2l, x2g, B);

    // ---- classifier ----
    classifier_k<<<(B + 31) / 32, TB, 0, stream>>>(x2g, Wc1, bc1, Wc2, bc2, out, B);
}

// Round 5
// 351.912 us; speedup vs baseline: 7.0038x; 1.1163x over previous
//
#include <hip/hip_runtime.h>
#include <hip/hip_bf16.h>

// Problem constants (match reference setup_inputs)
static constexpr int N = 100000;
static constexpr int E = 600000;
static constexpr int D = 128;
static constexpr int B = 10000;
static constexpr int C = 32;

typedef __attribute__((ext_vector_type(8))) short short8;   // 8 bf16 (4 VGPRs)
typedef __attribute__((ext_vector_type(4))) float f32x4;    // MFMA acc

// bf16 RNE helpers (bit-level, no NaN inputs here)
static __device__ __forceinline__ unsigned short f2bf(float f) {
    unsigned u = __float_as_uint(f);
    unsigned r = (u + 0x7FFFu + ((u >> 16) & 1u)) >> 16;
    return (unsigned short)r;
}
static __device__ __forceinline__ float bf2f(unsigned short h) {
    return __uint_as_float(((unsigned)h) << 16);
}

// split 8 consecutive floats into hi/lo bf16 fragments
static __device__ __forceinline__ void split8(const float4 v0, const float4 v1,
                                              short8& h, short8& l) {
    const float f[8] = {v0.x, v0.y, v0.z, v0.w, v1.x, v1.y, v1.z, v1.w};
    #pragma unroll
    for (int i = 0; i < 8; ++i) {
        unsigned short hh = f2bf(f[i]);
        h[i] = (short)hh;
        l[i] = (short)f2bf(f[i] - bf2f(hh));
    }
}

// ---------------- CSR build ----------------

__global__ void deg_k(const int* __restrict__ dst, int* __restrict__ deg, int nE) {
    int i = blockIdx.x * blockDim.x + threadIdx.x;
    if (i < nE) atomicAdd(&deg[dst[i]], 1);
}

__global__ __launch_bounds__(256) void scan1_k(const int* __restrict__ deg,
                                               int* __restrict__ bsum, int n) {
    __shared__ int lsum[256];
    const int t = threadIdx.x;
    const int base = blockIdx.x * 1024 + t * 4;
    int s = 0;
    #pragma unroll
    for (int i = 0; i < 4; ++i) {
        int idx = base + i;
        if (idx < n) s += deg[idx];
    }
    lsum[t] = s;
    __syncthreads();
    for (int off = 128; off > 0; off >>= 1) {
        if (t < off) lsum[t] += lsum[t + off];
        __syncthreads();
    }
    if (t == 0) bsum[blockIdx.x] = lsum[0];
}

__global__ __launch_bounds__(128) void scan2_k(const int* __restrict__ bsum,
                                               int* __restrict__ boff,
                                               int* __restrict__ roff, int nb, int n) {
    __shared__ int s[128];
    const int t = threadIdx.x;
    const int v = (t < nb) ? bsum[t] : 0;
    s[t] = v;
    __syncthreads();
    for (int off = 1; off < 128; off <<= 1) {
        int u = (t >= off) ? s[t - off] : 0;
        __syncthreads();
        s[t] += u;
        __syncthreads();
    }
    if (t < nb) boff[t] = s[t] - v;
    if (t == 127) roff[n] = s[127];
}

__global__ __launch_bounds__(256) void scan3_k(const int* __restrict__ deg,
                                               const int* __restrict__ boff,
                                               int* __restrict__ roff,
                                               int* __restrict__ cur, int n) {
    __shared__ int lsum[256];
    const int t = threadIdx.x;
    const int base = blockIdx.x * 1024 + t * 4;
    int d[4];
    int s = 0;
    #pragma unroll
    for (int i = 0; i < 4; ++i) {
        int idx = base + i;
        d[i] = (idx < n) ? deg[idx] : 0;
        s += d[i];
    }
    lsum[t] = s;
    __syncthreads();
    for (int off = 1; off < 256; off <<= 1) {
        int u = (t >= off) ? lsum[t - off] : 0;
        __syncthreads();
        lsum[t] += u;
        __syncthreads();
    }
    int run = boff[blockIdx.x] + lsum[t] - s;
    #pragma unroll
    for (int i = 0; i < 4; ++i) {
        int idx = base + i;
        if (idx < n) {
            roff[idx] = run;
            cur[idx]  = run;
            run += d[i];
        }
    }
}

__global__ void fill_k(const int* __restrict__ src, const int* __restrict__ dst,
                       int* __restrict__ cur, int* __restrict__ csr_src, int nE) {
    int e = blockIdx.x * blockDim.x + threadIdx.x;
    if (e < nE) {
        int p = atomicAdd(&cur[dst[e]], 1);
        csr_src[p] = src[e];
    }
}

// ---------------- weight swizzle: fp32 W[128][128] -> MFMA-B fragment order, hi/lo bf16 ----------------
// per matrix: out[plane][((ko*8+no)*64+lane)*8+j], value = W[ko*32+(lane>>4)*8+j][no*16+(lane&15)]
__global__ __launch_bounds__(256) void swz_k(const float* W0, const float* W1,
                                             const float* W2, const float* W3,
                                             unsigned short* __restrict__ out) {
    const float* W = (blockIdx.x == 0) ? W0 : (blockIdx.x == 1) ? W1
                   : (blockIdx.x == 2) ? W2 : W3;
    unsigned short* o = out + (size_t)blockIdx.x * 32768;
    #pragma unroll
    for (int it = 0; it < 64; ++it) {
        int f = threadIdx.x + it * 256;          // 0..16383
        int j = f & 7;
        int lane = (f >> 3) & 63;
        int fi = f >> 9;                         // 0..31 = ko*8+no
        int k = (fi >> 3) * 32 + (lane >> 4) * 8 + j;
        int n = (fi & 7) * 16 + (lane & 15);
        float a = W[k * 128 + n];
        unsigned short h = f2bf(a);
        unsigned short l = f2bf(a - bf2f(h));
        o[f] = h;
        o[16384 + f] = l;
    }
}

// ---------------- gather-mean aggregation ----------------
template <bool GATHER>
__global__ __launch_bounds__(256) void gather_mean_k(
    const float* __restrict__ x, const int* __restrict__ roff,
    const int* __restrict__ csr_src, const int* __restrict__ rows,
    float* __restrict__ out, int nrows) {
    const int w = blockIdx.x * (blockDim.x >> 6) + (threadIdx.x >> 6);
    if (w >= nrows) return;
    const int lane = threadIdx.x & 63;
    const int n  = GATHER ? rows[w] : w;
    const int jb = roff[n];
    const int je = roff[n + 1];
    const float* xb = x + lane * 2;

    float ax = 0.f, ay = 0.f;
    int j = jb;
    for (; j + 4 <= je; j += 4) {
        int s0 = csr_src[j + 0];
        int s1 = csr_src[j + 1];
        int s2 = csr_src[j + 2];
        int s3 = csr_src[j + 3];
        float2 v0 = *reinterpret_cast<const float2*>(xb + (size_t)s0 * D);
        float2 v1 = *reinterpret_cast<const float2*>(xb + (size_t)s1 * D);
        float2 v2 = *reinterpret_cast<const float2*>(xb + (size_t)s2 * D);
        float2 v3 = *reinterpret_cast<const float2*>(xb + (size_t)s3 * D);
        ax += v0.x + v1.x + v2.x + v3.x;
        ay += v0.y + v1.y + v2.y + v3.y;
    }
    for (; j < je; ++j) {
        int s = csr_src[j];
        float2 v = *reinterpret_cast<const float2*>(xb + (size_t)s * D);
        ax += v.x;
        ay += v.y;
    }
    const float inv = 1.0f / fmaxf((float)(je - jb), 1.0f);
    *reinterpret_cast<float2*>(out + (size_t)w * D + lane * 2) =
        make_float2(ax * inv, ay * inv);
}

// ---------------- SAGE layer, split-bf16 MFMA, LDS-free / barrier-free ----------------
// xout[row] = relu( mean[row]@Wl + bl + xin[grow]@Wr ), fp32-accurate via
// A@W ~= Ah@Wh + Al@Wh + Ah@Wl  (3-term hi/lo split, residual ~2^-18)
// Block: 128 rows x 128 cols, 4 independent waves (each 32 rows x 128 cols).
// A-frags: direct global->VGPR (lane reads 2 float4 of its own row), split in regs.
// B-frags: direct global loads of pre-swizzled fragment-order weights (L2-hot).
template <bool GATHER>
__global__ __launch_bounds__(256, 3) void sage_mfma_k(
    const float* __restrict__ mean, const float* __restrict__ xin,
    const int* __restrict__ rows,
    const unsigned short* __restrict__ WlSw, const unsigned short* __restrict__ WrSw,
    const float* __restrict__ bl, float* __restrict__ xout, int nrows)
{
    const int t = threadIdx.x;
    const int w = t >> 6;
    const int lane = t & 63;
    const int mcol = lane & 15;
    const int q = lane >> 4;
    const int rb = blockIdx.x * 128;

    f32x4 acc[2][8];
    #pragma unroll
    for (int mt = 0; mt < 2; ++mt)
        #pragma unroll
        for (int no = 0; no < 8; ++no)
            acc[mt][no] = (f32x4){0.f, 0.f, 0.f, 0.f};

    #pragma unroll
    for (int br = 0; br < 2; ++br) {
        const float* __restrict__ Asrc = br ? xin : mean;
        const unsigned short* __restrict__ Wm = br ? WrSw : WlSw;
        #pragma unroll
        for (int kp = 0; kp < 4; ++kp) {
            // ---- A fragments: global -> regs, split hi/lo
            short8 aH[2], aL[2];
            #pragma unroll
            for (int mt = 0; mt < 2; ++mt) {
                const int r = rb + w * 32 + mt * 16 + mcol;
                float4 v0 = make_float4(0.f, 0.f, 0.f, 0.f);
                float4 v1 = make_float4(0.f, 0.f, 0.f, 0.f);
                if (r < nrows) {
                    // mean is compact (index r); xin indexed through rows[] if GATHER
                    const size_t g = (size_t)((br && GATHER) ? rows[r] : r);
                    const float* p = Asrc + g * D + kp * 32 + q * 8;
                    v0 = *reinterpret_cast<const float4*>(p);
                    v1 = *reinterpret_cast<const float4*>(p + 4);
                }
                split8(v0, v1, aH[mt], aL[mt]);
            }
            // ---- MFMA over 8 col-tiles; B straight from L2 in fragment order
            #pragma unroll
            for (int no = 0; no < 8; ++no) {
                const size_t fo = ((size_t)(kp * 8 + no) * 64 + lane) * 8;
                short8 bh = *reinterpret_cast<const short8*>(Wm + fo);
                short8 bo = *reinterpret_cast<const short8*>(Wm + 16384 + fo);
                #pragma unroll
                for (int mt = 0; mt < 2; ++mt) {
                    acc[mt][no] = __builtin_amdgcn_mfma_f32_16x16x32_bf16(
                        aH[mt], bh, acc[mt][no], 0, 0, 0);
                    acc[mt][no] = __builtin_amdgcn_mfma_f32_16x16x32_bf16(
                        aL[mt], bh, acc[mt][no], 0, 0, 0);
                    acc[mt][no] = __builtin_amdgcn_mfma_f32_16x16x32_bf16(
                        aH[mt], bo, acc[mt][no], 0, 0, 0);
                }
            }
        }
    }

    // ---- epilogue: bias + relu + store (C/D layout: col=lane&15, row=q*4+reg)
    #pragma unroll
    for (int no = 0; no < 8; ++no) {
        const int col = no * 16 + mcol;
        const float bias = bl[col];
        #pragma unroll
        for (int mt = 0; mt < 2; ++mt) {
            #pragma unroll
            for (int r = 0; r < 4; ++r) {
                const int row = rb + w * 32 + mt * 16 + q * 4 + r;
                if (row < nrows)
                    xout[(size_t)row * D + col] = fmaxf(acc[mt][no][r] + bias, 0.f);
            }
        }
    }
}

// ---------------- classifier: out = relu(x2g@Wc1+bc1) @ Wc2 + bc2 ----------------
__global__ __launch_bounds__(256) void classifier_k(
    const float* __restrict__ x2g,
    const float* __restrict__ Wc1, const float* __restrict__ bc1,
    const float* __restrict__ Wc2, const float* __restrict__ bc2,
    float* __restrict__ out, int nrows) {
    __shared__ float Xs[32][128];
    __shared__ float Hs[32][128];
    const int rb = blockIdx.x * 32;
    const int t  = threadIdx.x;

    #pragma unroll
    for (int it = 0; it < 4; ++it) {
        int j  = t + it * 256;
        int r  = j >> 5;
        int k4 = j & 31;
        int row = rb + r;
        float4 v = make_float4(0.f, 0.f, 0.f, 0.f);
        if (row < nrows) v = *reinterpret_cast<const float4*>(x2g + (size_t)row * D + k4 * 4);
        *reinterpret_cast<float4*>(&Xs[r][k4 * 4]) = v;
    }
    __syncthreads();

    {
        const int col  = t & 127;
        const int half = t >> 7;
        float acc[16];
        const float bias = bc1[col];
        #pragma unroll
        for (int i = 0; i < 16; ++i) acc[i] = bias;
        for (int k = 0; k < 128; ++k) {
            float w = Wc1[k * 128 + col];
            #pragma unroll
            for (int i = 0; i < 16; ++i)
                acc[i] = fmaf(Xs[half * 16 + i][k], w, acc[i]);
        }
        #pragma unroll
        for (int i = 0; i < 16; ++i)
            Hs[half * 16 + i][col] = fmaxf(acc[i], 0.0f);
    }
    __syncthreads();

    {
        const int c  = t & 31;
        const int rg = t >> 5;
        float o[4];
        const float b2 = bc2[c];
        #pragma unroll
        for (int i = 0; i < 4; ++i) o[i] = b2;
        for (int k = 0; k < 128; ++k) {
            float w = Wc2[k * 32 + c];
            #pragma unroll
            for (int i = 0; i < 4; ++i)
                o[i] = fmaf(Hs[rg + 8 * i][k], w, o[i]);
        }
        #pragma unroll
        for (int i = 0; i < 4; ++i) {
            int row = rb + rg + 8 * i;
            if (row < nrows) out[(size_t)row * C + c] = o[i];
        }
    }
}

// ---------------- launch ----------------

extern "C" void kernel_launch(void* const* d_in, const int* in_sizes, int n_in,
                              void* d_out, int out_size, void* d_ws, size_t ws_size,
                              hipStream_t stream) {
    const float* node_state = (const float*)d_in[0];
    const int*   edge_index = (const int*)d_in[1];
    const int*   label_pos  = (const int*)d_in[2];
    const float* W1l = (const float*)d_in[3];
    const float* b1l = (const float*)d_in[4];
    const float* W1r = (const float*)d_in[5];
    const float* W2l = (const float*)d_in[6];
    const float* b2l = (const float*)d_in[7];
    const float* W2r = (const float*)d_in[8];
    const float* Wc1 = (const float*)d_in[9];
    const float* bc1 = (const float*)d_in[10];
    const float* Wc2 = (const float*)d_in[11];
    const float* bc2 = (const float*)d_in[12];
    float* out = (float*)d_out;

    const int* src = edge_index;       // edge_index[0]
    const int* dst = edge_index + E;   // edge_index[1]

    // workspace layout (floats first for alignment)
    char* ws = (char*)d_ws;
    float* bufA  = (float*)ws;                    ws += sizeof(float) * (size_t)N * D;
    float* x1    = (float*)ws;                    ws += sizeof(float) * (size_t)N * D;
    unsigned short* Wsw = (unsigned short*)ws;    ws += sizeof(unsigned short) * 4 * 32768;
    int* deg     = (int*)ws;                      ws += sizeof(int) * N;
    int* roff    = (int*)ws;                      ws += sizeof(int) * (N + 1);
    int* cur     = (int*)ws;                      ws += sizeof(int) * N;
    int* csr_src = (int*)ws;                      ws += sizeof(int) * E;
    int* bsum    = (int*)ws;                      ws += sizeof(int) * 128;
    int* boff    = (int*)ws;                      ws += sizeof(int) * 128;
    // bufA: mean1 [N][D] for layer 1; then mean2g [B][D] + x2g [B][D]
    float* mean1  = bufA;
    float* mean2g = bufA;
    float* x2g    = bufA + (size_t)B * D;

    const int TB = 256;
    const int NB = (N + 1023) / 1024;

    // ---- CSR build ----
    hipMemsetAsync(deg, 0, sizeof(int) * N, stream);
    deg_k<<<(E + TB - 1) / TB, TB, 0, stream>>>(dst, deg, E);
    scan1_k<<<NB, 256, 0, stream>>>(deg, bsum, N);
    scan2_k<<<1, 128, 0, stream>>>(bsum, boff, roff, NB, N);
    scan3_k<<<NB, 256, 0, stream>>>(deg, boff, roff, cur, N);
    fill_k<<<(E + TB - 1) / TB, TB, 0, stream>>>(src, dst, cur, csr_src, E);

    // ---- weight swizzle (W1l, W1r, W2l, W2r) ----
    swz_k<<<4, 256, 0, stream>>>(W1l, W1r, W2l, W2r, Wsw);

    // ---- layer 1 ----
    gather_mean_k<false><<<(N + 3) / 4, TB, 0, stream>>>(
        node_state, roff, csr_src, nullptr, mean1, N);
    sage_mfma_k<false><<<(N + 127) / 128, TB, 0, stream>>>(
        mean1, node_state, nullptr, Wsw, Wsw + 32768, b1l, x1, N);

    // ---- layer 2 (only label rows) ----
    gather_mean_k<true><<<(B + 3) / 4, TB, 0, stream>>>(
        x1, roff, csr_src, label_pos, mean2g, B);
    sage_mfma_k<true><<<(B + 127) / 128, TB, 0, stream>>>(
        mean2g, x1, label_pos, Wsw + 65536, Wsw + 98304, b2l, x2g, B);

    // ---- classifier ----
    classifier_k<<<(B + 31) / 32, TB, 0, stream>>>(x2g, Wc1, bc1, Wc2, bc2, out, B);
}